// Round 1
// baseline (343.679 us; speedup 1.0000x reference)
//
#include <hip/hip_runtime.h>

// Pipeline is fully linear in `project`. Fold everything into Cmat[10][C*H*W]
// on-device each call, then one memory-bound pass over project (205 MB).
//
// ws layout (floats):
//   A0   [10][196][512]  spread(wh)                 off 0
//   A1   [10][196][512]  fold(A0, w3)               off 1003520
//   A2   [10][196][512]  fold(A1, w2)               off 2007040
//   Cmat [10][c*196+hw]  fold(A2, w1), transposed   off 3010560
//   dvec [16]            bias folds                 off 4014080
//   part [32][512][10]   segment partials           off 4014096
// total 4,177,936 floats = 16.7 MB

#define CHW 100352   // 512*196
#define STEP 1.8571428571428572f  // 13/7

__device__ __forceinline__ float edge_w(int p, float s, int lim) {
    // contribution weight of image row/col p from sample coordinate s
    float f = floorf(s);
    float wfrac = s - f;
    int a = (int)f;
    int b = a + 1;
    a = min(max(a, 0), lim); b = min(max(b, 0), lim);
    float c = 0.f;
    if (p == a) c += 1.f - wfrac;
    if (p == b) c += wfrac;
    return c;
}

// A0[k][hw][o] = sum_{j,i} wh[k][o*49 + j*7+i] * cy(j,h) * cx(i,w)
__global__ void k_spread(const float* __restrict__ w_note,
                         const float* __restrict__ w_reg,
                         float* __restrict__ A0) {
    int tid = blockIdx.x * 256 + threadIdx.x;
    int o  = tid & 511;
    int hw = (tid >> 9) % 196;
    int k  = tid / CHW;
    int h = hw / 14, w = hw % 14;
    const float* wh = (k < 2) ? (w_note + k * 25088) : (w_reg + (k - 2) * 25088);
    const float base = STEP * 0.5f - 0.5f;
    float acc = 0.f;
    for (int j = 0; j < 7; ++j) {
        float cy = edge_w(h, base + j * STEP, 13);
        if (cy == 0.f) continue;
        for (int i = 0; i < 7; ++i) {
            float cx = edge_w(w, base + i * STEP, 13);
            if (cx != 0.f) acc += cy * cx * wh[o * 49 + j * 7 + i];
        }
    }
    A0[tid] = acc;
}

// Aout[k][hw][c] = sum_o Ain[k][hw][o] * Wm[o*512 + c]
// FINAL=true writes Cmat layout [k][c*196 + hw] instead.
template <bool FINAL>
__global__ void k_fold(const float* __restrict__ Ain,
                       const float* __restrict__ Wm,
                       float* __restrict__ Aout) {
    __shared__ float lds[512][12];
    int hw = blockIdx.x;
    int c = threadIdx.x;  // 512 threads
    #pragma unroll
    for (int k = 0; k < 10; ++k)
        lds[c][k] = Ain[k * CHW + hw * 512 + c];
    __syncthreads();
    float a0 = 0.f, a1 = 0.f, a2 = 0.f, a3 = 0.f, a4 = 0.f;
    float a5 = 0.f, a6 = 0.f, a7 = 0.f, a8 = 0.f, a9 = 0.f;
    #pragma unroll 4
    for (int o = 0; o < 512; ++o) {
        float wv = Wm[o * 512 + c];
        const float4* row = (const float4*)lds[o];
        float4 r0 = row[0];
        float4 r1 = row[1];
        float2 r2 = *(const float2*)&lds[o][8];
        a0 += r0.x * wv; a1 += r0.y * wv; a2 += r0.z * wv; a3 += r0.w * wv;
        a4 += r1.x * wv; a5 += r1.y * wv; a6 += r1.z * wv; a7 += r1.w * wv;
        a8 += r2.x * wv; a9 += r2.y * wv;
    }
    if (FINAL) {
        int idx = c * 196 + hw;
        Aout[0 * CHW + idx] = a0; Aout[1 * CHW + idx] = a1;
        Aout[2 * CHW + idx] = a2; Aout[3 * CHW + idx] = a3;
        Aout[4 * CHW + idx] = a4; Aout[5 * CHW + idx] = a5;
        Aout[6 * CHW + idx] = a6; Aout[7 * CHW + idx] = a7;
        Aout[8 * CHW + idx] = a8; Aout[9 * CHW + idx] = a9;
    } else {
        int idx = hw * 512 + c;
        Aout[0 * CHW + idx] = a0; Aout[1 * CHW + idx] = a1;
        Aout[2 * CHW + idx] = a2; Aout[3 * CHW + idx] = a3;
        Aout[4 * CHW + idx] = a4; Aout[5 * CHW + idx] = a5;
        Aout[6 * CHW + idx] = a6; Aout[7 * CHW + idx] = a7;
        Aout[8 * CHW + idx] = a8; Aout[9 * CHW + idx] = a9;
    }
}

// d[k] = bh[k] + sum wh*b3 + sum A1*b2 + sum A2*b1
__global__ void k_bias(const float* __restrict__ w_note, const float* __restrict__ w_reg,
                       const float* __restrict__ b_note, const float* __restrict__ b_reg,
                       const float* __restrict__ b1, const float* __restrict__ b2,
                       const float* __restrict__ b3,
                       const float* __restrict__ A1, const float* __restrict__ A2,
                       float* __restrict__ dvec) {
    int k = blockIdx.x;
    int t = threadIdx.x;
    const float* wh = (k < 2) ? (w_note + k * 25088) : (w_reg + (k - 2) * 25088);
    float s = 0.f;
    for (int i = t; i < 25088; i += 256) s += wh[i] * b3[i / 49];
    for (int i = t; i < CHW; i += 256) {
        s += A1[k * CHW + i] * b2[i & 511];
        s += A2[k * CHW + i] * b1[i & 511];
    }
    __shared__ float red[256];
    red[t] = s;
    __syncthreads();
    for (int off = 128; off; off >>= 1) {
        if (t < off) red[t] += red[t + off];
        __syncthreads();
    }
    if (t == 0) dvec[k] = red[0] + ((k < 2) ? b_note[k] : b_reg[k - 2]);
}

// partials[s][n][k] = sum over segment s of Cmat[k]·project[n]
__global__ __launch_bounds__(256) void k_main(const float* __restrict__ proj,
                                              const float* __restrict__ Cmat,
                                              float* __restrict__ partials) {
    int s = blockIdx.x;   // 32 segments of 3136 chw
    int g = blockIdx.y;   // 32 groups of 16 n
    int tid = threadIdx.x;
    int nl = tid >> 4, t = tid & 15;
    int n = g * 16 + nl;
    const float* pn = proj + (size_t)n * CHW;
    int base = s * 3136 + t * 4;
    float acc[10];
    #pragma unroll
    for (int k = 0; k < 10; ++k) acc[k] = 0.f;
    for (int it = 0; it < 49; ++it) {
        int chw = base + it * 64;
        float4 p = *(const float4*)(pn + chw);
        #pragma unroll
        for (int k = 0; k < 10; ++k) {
            float4 cm = *(const float4*)(Cmat + k * CHW + chw);
            acc[k] += p.x * cm.x + p.y * cm.y + p.z * cm.z + p.w * cm.w;
        }
    }
    #pragma unroll
    for (int k = 0; k < 10; ++k) {
        float v = acc[k];
        v += __shfl_xor(v, 1, 16);
        v += __shfl_xor(v, 2, 16);
        v += __shfl_xor(v, 4, 16);
        v += __shfl_xor(v, 8, 16);
        if (t == 0) partials[(s * 512 + n) * 10 + k] = v;
    }
}

__global__ void k_reduce(const float* __restrict__ partials,
                         const float* __restrict__ dvec,
                         float* __restrict__ out) {
    int idx = blockIdx.x * 256 + threadIdx.x;  // 0..5119
    int n = idx / 10, k = idx % 10;
    float s = dvec[k];
    for (int seg = 0; seg < 32; ++seg) s += partials[(seg * 512 + n) * 10 + k];
    if (k < 2) out[n * 2 + k] = s;
    else       out[1024 + n * 8 + (k - 2)] = s;
}

extern "C" void kernel_launch(void* const* d_in, const int* in_sizes, int n_in,
                              void* d_out, int out_size, void* d_ws, size_t ws_size,
                              hipStream_t stream) {
    const float* proj   = (const float*)d_in[0];
    const float* w1     = (const float*)d_in[1];
    const float* b1     = (const float*)d_in[2];
    const float* w2     = (const float*)d_in[3];
    const float* b2     = (const float*)d_in[4];
    const float* w3     = (const float*)d_in[5];
    const float* b3     = (const float*)d_in[6];
    const float* w_note = (const float*)d_in[7];
    const float* b_note = (const float*)d_in[8];
    const float* w_reg  = (const float*)d_in[9];
    const float* b_reg  = (const float*)d_in[10];

    float* ws   = (float*)d_ws;
    float* A0   = ws;
    float* A1   = A0 + 1003520;
    float* A2   = A1 + 1003520;
    float* Cm   = A2 + 1003520;
    float* dvec = Cm + 1003520;
    float* part = dvec + 16;
    float* out  = (float*)d_out;

    k_spread<<<3920, 256, 0, stream>>>(w_note, w_reg, A0);
    k_fold<false><<<196, 512, 0, stream>>>(A0, w3, A1);
    k_fold<false><<<196, 512, 0, stream>>>(A1, w2, A2);
    k_bias<<<10, 256, 0, stream>>>(w_note, w_reg, b_note, b_reg, b1, b2, b3, A1, A2, dvec);
    k_fold<true><<<196, 512, 0, stream>>>(A2, w1, Cm);
    k_main<<<dim3(32, 32), 256, 0, stream>>>(proj, Cm, part);
    k_reduce<<<20, 256, 0, stream>>>(part, dvec, out);
}

// Round 2
// 219.309 us; speedup vs baseline: 1.5671x; 1.5671x over previous
//
#include <hip/hip_runtime.h>

// Pipeline is fully linear in `project`. Fold everything into Cmat[10][C*H*W]
// on-device each call, then one memory-bound pass over project (205 MB).
//
// ws layout (floats):
//   A0    [10][196][512]  spread(wh)                 off 0
//   A1    [10][196][512]  fold(A0, w3)               off 1003520
//   A2    [10][196][512]  fold(A1, w2)               off 2007040
//   Cmat  [10][c*196+hw]  fold(A2, w1), transposed   off 3010560
//   dpart [10][32]        bias partials              off 4014080
//   part  [32][512][10]   segment partials           off 4014400

#define CHW 100352   // 512*196
#define STEP 1.8571428571428572f  // 13/7

__device__ __forceinline__ float edge_w(int p, float s, int lim) {
    float f = floorf(s);
    float wfrac = s - f;
    int a = (int)f;
    int b = a + 1;
    a = min(max(a, 0), lim); b = min(max(b, 0), lim);
    float c = 0.f;
    if (p == a) c += 1.f - wfrac;
    if (p == b) c += wfrac;
    return c;
}

// A0[k][hw][o] = sum_{j,i} wh[k][o*49 + j*7+i] * cy(j,h) * cx(i,w)
__global__ void k_spread(const float* __restrict__ w_note,
                         const float* __restrict__ w_reg,
                         float* __restrict__ A0) {
    int tid = blockIdx.x * 256 + threadIdx.x;
    int o  = tid & 511;
    int hw = (tid >> 9) % 196;
    int k  = tid / CHW;
    int h = hw / 14, w = hw % 14;
    const float* wh = (k < 2) ? (w_note + k * 25088) : (w_reg + (k - 2) * 25088);
    const float base = STEP * 0.5f - 0.5f;
    float acc = 0.f;
    for (int j = 0; j < 7; ++j) {
        float cy = edge_w(h, base + j * STEP, 13);
        if (cy == 0.f) continue;
        for (int i = 0; i < 7; ++i) {
            float cx = edge_w(w, base + i * STEP, 13);
            if (cx != 0.f) acc += cy * cx * wh[o * 49 + j * 7 + i];
        }
    }
    A0[tid] = acc;
}

// Aout[k][hw][c] = sum_o Ain[k][hw][o] * Wm[o*512 + c]
// FINAL=true writes Cmat layout [k][c*196 + hw] instead.
template <bool FINAL>
__global__ void k_fold(const float* __restrict__ Ain,
                       const float* __restrict__ Wm,
                       float* __restrict__ Aout) {
    __shared__ float lds[512][12];
    int hw = blockIdx.x;
    int c = threadIdx.x;  // 512 threads
    #pragma unroll
    for (int k = 0; k < 10; ++k)
        lds[c][k] = Ain[k * CHW + hw * 512 + c];
    __syncthreads();
    float a0 = 0.f, a1 = 0.f, a2 = 0.f, a3 = 0.f, a4 = 0.f;
    float a5 = 0.f, a6 = 0.f, a7 = 0.f, a8 = 0.f, a9 = 0.f;
    #pragma unroll 4
    for (int o = 0; o < 512; ++o) {
        float wv = Wm[o * 512 + c];
        const float4* row = (const float4*)lds[o];
        float4 r0 = row[0];
        float4 r1 = row[1];
        float2 r2 = *(const float2*)&lds[o][8];
        a0 += r0.x * wv; a1 += r0.y * wv; a2 += r0.z * wv; a3 += r0.w * wv;
        a4 += r1.x * wv; a5 += r1.y * wv; a6 += r1.z * wv; a7 += r1.w * wv;
        a8 += r2.x * wv; a9 += r2.y * wv;
    }
    if (FINAL) {
        int idx = c * 196 + hw;
        Aout[0 * CHW + idx] = a0; Aout[1 * CHW + idx] = a1;
        Aout[2 * CHW + idx] = a2; Aout[3 * CHW + idx] = a3;
        Aout[4 * CHW + idx] = a4; Aout[5 * CHW + idx] = a5;
        Aout[6 * CHW + idx] = a6; Aout[7 * CHW + idx] = a7;
        Aout[8 * CHW + idx] = a8; Aout[9 * CHW + idx] = a9;
    } else {
        int idx = hw * 512 + c;
        Aout[0 * CHW + idx] = a0; Aout[1 * CHW + idx] = a1;
        Aout[2 * CHW + idx] = a2; Aout[3 * CHW + idx] = a3;
        Aout[4 * CHW + idx] = a4; Aout[5 * CHW + idx] = a5;
        Aout[6 * CHW + idx] = a6; Aout[7 * CHW + idx] = a7;
        Aout[8 * CHW + idx] = a8; Aout[9 * CHW + idx] = a9;
    }
}

// dpart[k][b] = partial of (sum wh*b3 + sum A1*b2 + sum A2*b1)
__global__ void k_bias_part(const float* __restrict__ w_note, const float* __restrict__ w_reg,
                            const float* __restrict__ b1, const float* __restrict__ b2,
                            const float* __restrict__ b3,
                            const float* __restrict__ A1, const float* __restrict__ A2,
                            float* __restrict__ dpart) {
    int k = blockIdx.x;   // 10
    int b = blockIdx.y;   // 32
    int t = threadIdx.x;  // 256
    const float* wh = (k < 2) ? (w_note + k * 25088) : (w_reg + (k - 2) * 25088);
    float s = 0.f;
    for (int i = b * 256 + t; i < 25088; i += 8192) s += wh[i] * b3[i / 49];
    for (int i = b * 256 + t; i < CHW; i += 8192) {
        s += A1[k * CHW + i] * b2[i & 511];
        s += A2[k * CHW + i] * b1[i & 511];
    }
    __shared__ float red[256];
    red[t] = s;
    __syncthreads();
    for (int off = 128; off; off >>= 1) {
        if (t < off) red[t] += red[t + off];
        __syncthreads();
    }
    if (t == 0) dpart[k * 32 + b] = red[0];
}

// partials[s][n][k] = sum over segment s of Cmat[k]·project[n]
__global__ __launch_bounds__(256) void k_main(const float* __restrict__ proj,
                                              const float* __restrict__ Cmat,
                                              float* __restrict__ partials) {
    int s = blockIdx.x;   // 32 segments of 3136 chw
    int g = blockIdx.y;   // 32 groups of 16 n
    int tid = threadIdx.x;
    int nl = tid >> 4, t = tid & 15;
    int n = g * 16 + nl;
    const float* pn = proj + (size_t)n * CHW;
    int base = s * 3136 + t * 4;
    float acc[10];
    #pragma unroll
    for (int k = 0; k < 10; ++k) acc[k] = 0.f;
    for (int it = 0; it < 49; ++it) {
        int chw = base + it * 64;
        float4 p = *(const float4*)(pn + chw);
        #pragma unroll
        for (int k = 0; k < 10; ++k) {
            float4 cm = *(const float4*)(Cmat + k * CHW + chw);
            acc[k] += p.x * cm.x + p.y * cm.y + p.z * cm.z + p.w * cm.w;
        }
    }
    #pragma unroll
    for (int k = 0; k < 10; ++k) {
        float v = acc[k];
        v += __shfl_xor(v, 1, 16);
        v += __shfl_xor(v, 2, 16);
        v += __shfl_xor(v, 4, 16);
        v += __shfl_xor(v, 8, 16);
        if (t == 0) partials[(s * 512 + n) * 10 + k] = v;
    }
}

__global__ void k_reduce(const float* __restrict__ partials,
                         const float* __restrict__ dpart,
                         const float* __restrict__ b_note, const float* __restrict__ b_reg,
                         float* __restrict__ out) {
    int idx = blockIdx.x * 256 + threadIdx.x;  // 0..5119
    int n = idx / 10, k = idx % 10;
    float s = (k < 2) ? b_note[k] : b_reg[k - 2];
    for (int b = 0; b < 32; ++b) s += dpart[k * 32 + b];
    for (int seg = 0; seg < 32; ++seg) s += partials[(seg * 512 + n) * 10 + k];
    if (k < 2) out[n * 2 + k] = s;
    else       out[1024 + n * 8 + (k - 2)] = s;
}

extern "C" void kernel_launch(void* const* d_in, const int* in_sizes, int n_in,
                              void* d_out, int out_size, void* d_ws, size_t ws_size,
                              hipStream_t stream) {
    const float* proj   = (const float*)d_in[0];
    const float* w1     = (const float*)d_in[1];
    const float* b1     = (const float*)d_in[2];
    const float* w2     = (const float*)d_in[3];
    const float* b2     = (const float*)d_in[4];
    const float* w3     = (const float*)d_in[5];
    const float* b3     = (const float*)d_in[6];
    const float* w_note = (const float*)d_in[7];
    const float* b_note = (const float*)d_in[8];
    const float* w_reg  = (const float*)d_in[9];
    const float* b_reg  = (const float*)d_in[10];

    float* ws    = (float*)d_ws;
    float* A0    = ws;
    float* A1    = A0 + 1003520;
    float* A2    = A1 + 1003520;
    float* Cm    = A2 + 1003520;
    float* dpart = Cm + 1003520;
    float* part  = dpart + 320;
    float* out   = (float*)d_out;

    k_spread<<<3920, 256, 0, stream>>>(w_note, w_reg, A0);
    k_fold<false><<<196, 512, 0, stream>>>(A0, w3, A1);
    k_fold<false><<<196, 512, 0, stream>>>(A1, w2, A2);
    k_bias_part<<<dim3(10, 32), 256, 0, stream>>>(w_note, w_reg, b1, b2, b3, A1, A2, dpart);
    k_fold<true><<<196, 512, 0, stream>>>(A2, w1, Cm);
    k_main<<<dim3(32, 32), 256, 0, stream>>>(proj, Cm, part);
    k_reduce<<<20, 256, 0, stream>>>(part, dpart, b_note, b_reg, out);
}